// Round 5
// baseline (705.552 us; speedup 1.0000x reference)
//
#include <hip/hip_runtime.h>

#define TOKENS 4096
#define DM 1024
#define DFF 2048
#define NE 8
#define CAP 2048

typedef unsigned short u16;
typedef __attribute__((ext_vector_type(8))) __bf16 bf16x8;
typedef __attribute__((ext_vector_type(8))) unsigned short u16x8;
typedef __attribute__((ext_vector_type(4))) float f32x4;

// async global->LDS, 16B per lane; LDS dest must be wave-uniform base (HW adds lane*16)
#define GL16(g, l)                                                                        \
  __builtin_amdgcn_global_load_lds((const __attribute__((address_space(1))) void*)(g),    \
                                   (__attribute__((address_space(3))) void*)(l), 16, 0, 0)

__device__ __forceinline__ u16 f2bf(float f) {
  unsigned int u = __builtin_bit_cast(unsigned int, f);
  unsigned int r = (u + 0x7FFFu + ((u >> 16) & 1u)) >> 16;
  return (u16)r;
}
__device__ __forceinline__ float bf2f(u16 h) {
  unsigned int u = ((unsigned int)h) << 16;
  return __builtin_bit_cast(float, u);
}

// ---------------- init ----------------
__global__ void zero_k(int* counters) {
  if (threadIdx.x < NE) counters[threadIdx.x] = 0;
}

// ---------------- fp32 -> bf16 convert (no transpose) ----------------
__global__ void conv_k(const float* __restrict__ src, u16* __restrict__ dst, int n4) {
  int i = blockIdx.x * 256 + threadIdx.x;
  if (i >= n4) return;
  float4 v = ((const float4*)src)[i];
  ushort4 ov = make_ushort4(f2bf(v.x), f2bf(v.y), f2bf(v.z), f2bf(v.w));
  ((ushort4*)dst)[i] = ov;
}

// ------------- fp32 [z][K][N] -> bf16 [z][N][K] transpose-convert -------------
__global__ void tconv_k(const float* __restrict__ src, u16* __restrict__ dst, int K, int N) {
  __shared__ u16 tile[64][68];
  const int k0 = blockIdx.x * 64;
  const int n0 = blockIdx.y * 64;
  const size_t zoff = (size_t)blockIdx.z * K * N;
  const float* s = src + zoff;
  u16* d = dst + zoff;
  const int tid = threadIdx.x;
#pragma unroll
  for (int p = 0; p < 4; ++p) {
    int idx = p * 256 + tid;
    int kr = idx >> 4;
    int nc = (idx & 15) * 4;
    float4 v = *(const float4*)(s + (size_t)(k0 + kr) * N + (n0 + nc));
    tile[kr][nc + 0] = f2bf(v.x);
    tile[kr][nc + 1] = f2bf(v.y);
    tile[kr][nc + 2] = f2bf(v.z);
    tile[kr][nc + 3] = f2bf(v.w);
  }
  __syncthreads();
#pragma unroll
  for (int p = 0; p < 4; ++p) {
    int idx = p * 256 + tid;
    int nr = idx >> 4;
    int kc = (idx & 15) * 4;
    ushort4 ov = make_ushort4(tile[kc + 0][nr], tile[kc + 1][nr], tile[kc + 2][nr], tile[kc + 3][nr]);
    *(ushort4*)(d + (size_t)(n0 + nr) * K + (k0 + kc)) = ov;
  }
}

// ---------------- router: logits, probs, lse, top-2, slot assignment ----------------
__global__ void router_k(const float* __restrict__ x, const float* __restrict__ Wr,
                         int* __restrict__ counters, int* __restrict__ tok_list,
                         int* __restrict__ tok_e, int* __restrict__ tok_slot,
                         float* __restrict__ tok_gate, float* __restrict__ tok_probs,
                         float* __restrict__ tok_lse) {
  const int t = blockIdx.x;
  const int l = threadIdx.x;
  float acc[NE];
#pragma unroll
  for (int e = 0; e < NE; ++e) acc[e] = 0.f;
  const float* xr = x + (size_t)t * DM;
#pragma unroll
  for (int it = 0; it < DM / 64; ++it) {
    int d = it * 64 + l;
    float xv = xr[d];
    const float4* wr = (const float4*)(Wr + (size_t)d * NE);
    float4 w0 = wr[0], w1 = wr[1];
    acc[0] += xv * w0.x; acc[1] += xv * w0.y; acc[2] += xv * w0.z; acc[3] += xv * w0.w;
    acc[4] += xv * w1.x; acc[5] += xv * w1.y; acc[6] += xv * w1.z; acc[7] += xv * w1.w;
  }
#pragma unroll
  for (int off = 32; off >= 1; off >>= 1) {
#pragma unroll
    for (int e = 0; e < NE; ++e) acc[e] += __shfl_xor(acc[e], off, 64);
  }
  if (l == 0) {
    float m = acc[0];
#pragma unroll
    for (int e = 1; e < NE; ++e) m = fmaxf(m, acc[e]);
    float ex[NE], s = 0.f;
#pragma unroll
    for (int e = 0; e < NE; ++e) { ex[e] = expf(acc[e] - m); s += ex[e]; }
    float inv = 1.f / s;
#pragma unroll
    for (int e = 0; e < NE; ++e) tok_probs[t * NE + e] = ex[e] * inv;
    tok_lse[t] = m + logf(s);
    // top-2 (ties -> lowest index, matching jax.lax.top_k)
    int i0 = 0; float l0 = acc[0];
#pragma unroll
    for (int e = 1; e < NE; ++e) if (acc[e] > l0) { l0 = acc[e]; i0 = e; }
    int i1 = -1; float l1 = -3.0e38f;
#pragma unroll
    for (int e = 0; e < NE; ++e) if (e != i0 && acc[e] > l1) { l1 = acc[e]; i1 = e; }
    float e1 = expf(l1 - l0);
    float g0 = 1.f / (1.f + e1);
    float g1 = e1 / (1.f + e1);
    int p0 = atomicAdd(&counters[i0], 1);
    int p1 = atomicAdd(&counters[i1], 1);
    if (p0 < CAP) tok_list[i0 * CAP + p0] = t;
    if (p1 < CAP) tok_list[i1 * CAP + p1] = t;
    tok_e[t * 2 + 0] = i0; tok_e[t * 2 + 1] = i1;
    tok_slot[t * 2 + 0] = p0; tok_slot[t * 2 + 1] = p1;
    tok_gate[t * 2 + 0] = g0; tok_gate[t * 2 + 1] = g1;
  }
}

// ---------------- loss finalize ----------------
__global__ void finalize_k(const float* __restrict__ tok_probs, const float* __restrict__ tok_lse,
                           const int* __restrict__ counters, float* __restrict__ tail) {
  __shared__ float s_p[NE];
  __shared__ float s_z;
  const int tid = threadIdx.x;
  if (tid == 0) s_z = 0.f;
  if (tid < NE) s_p[tid] = 0.f;
  __syncthreads();
  float lp[NE] = {0, 0, 0, 0, 0, 0, 0, 0};
  float lz = 0.f;
  for (int t = tid; t < TOKENS; t += 256) {
    float l = tok_lse[t];
    lz += l * l;
#pragma unroll
    for (int e = 0; e < NE; ++e) lp[e] += tok_probs[t * NE + e];
  }
#pragma unroll
  for (int off = 32; off >= 1; off >>= 1) {
    lz += __shfl_xor(lz, off, 64);
#pragma unroll
    for (int e = 0; e < NE; ++e) lp[e] += __shfl_xor(lp[e], off, 64);
  }
  if ((tid & 63) == 0) {
    atomicAdd(&s_z, lz);
    for (int e = 0; e < NE; ++e) atomicAdd(&s_p[e], lp[e]);
  }
  __syncthreads();
  if (tid == 0) {
    float z = s_z / (float)TOKENS;
    float lb = 0.f;
    for (int e = 0; e < NE; ++e) {
      float f = (float)counters[e] / (float)(TOKENS * 2);
      float p = s_p[e] / (float)TOKENS;
      lb += p * f;
      tail[e] = f;
    }
    lb *= (float)NE;
    tail[8] = z;
    tail[9] = z * 0.001f;
    tail[10] = lb;
    tail[11] = lb * 0.1f;
  }
}

// ---------------- GEMM1: H = silu(A@W1) * (A@W3);  A gathered rows of xb ----------------
// A: [*][1024] bf16 row-major. B1,B3: [e][2048][1024] bf16 ([N][K]). Hout: [e*CAP|M][2048] bf16
// Staging: global_load_lds width-16 (m97 pattern). Tile [128][32] u16 = 8 chunks of 1024B;
// wave w stages chunks {2w, 2w+1}; lane l -> row c*16 + l/4, 16B seg l&3 (linear: base+l*16).
__launch_bounds__(256, 2)
__global__ void gemm1_k(const u16* __restrict__ A, const u16* __restrict__ B1g,
                        const u16* __restrict__ B3g, u16* __restrict__ Hout,
                        const int* __restrict__ tok_list, const int* __restrict__ counts,
                        int Mfix) {
  constexpr int K = DM;
  constexpr int N = DFF;
  const int e = blockIdx.z;
  int n_e = counts ? counts[e] : Mfix;
  if (counts && n_e > CAP) n_e = CAP;  // capacity clamp ONLY for routed experts
  const int m_base = blockIdx.x * 128;
  if (m_base >= n_e) return;
  const int n_base = blockIdx.y * 128;
  const size_t bstride = counts ? (size_t)N * K : 0;
  const u16* B1 = B1g + (size_t)e * bstride;
  const u16* B3 = B3g + (size_t)e * bstride;

  __shared__ __align__(16) u16 Als[128 * 32];
  __shared__ __align__(16) u16 B1ls[128 * 32];
  __shared__ __align__(16) u16 B3ls[128 * 32];

  const int tid = threadIdx.x;
  const int lane = tid & 63;
  const int w = tid >> 6;
  const int wm = w >> 1, wn = w & 1;
  const int lo = lane & 15, hi = lane >> 4;

  // ---- staging geometry ----
  const int c0 = 2 * w;                 // first chunk for this wave
  const int r0 = c0 * 16 + (lane >> 2); // tile row for chunk c0
  const int r1 = r0 + 16;               // tile row for chunk c0+1
  const int sg = lane & 3;              // 16B segment within 64B row

  size_t ar0, ar1;
  if (tok_list) {
    int g0i = m_base + r0; if (g0i >= n_e) g0i = n_e - 1;
    int g1i = m_base + r1; if (g1i >= n_e) g1i = n_e - 1;
    ar0 = (size_t)tok_list[e * CAP + g0i];
    ar1 = (size_t)tok_list[e * CAP + g1i];
  } else {
    ar0 = (size_t)(m_base + r0);
    ar1 = (size_t)(m_base + r1);
  }
  const u16* pA0 = A + ar0 * (size_t)K + sg * 8;
  const u16* pA1 = A + ar1 * (size_t)K + sg * 8;
  const u16* pB1a = B1 + (size_t)(n_base + r0) * K + sg * 8;
  const u16* pB1b = B1 + (size_t)(n_base + r1) * K + sg * 8;
  const u16* pB3a = B3 + (size_t)(n_base + r0) * K + sg * 8;
  const u16* pB3b = B3 + (size_t)(n_base + r1) * K + sg * 8;
  u16* lA0 = &Als[c0 * 512];  u16* lA1 = &Als[c0 * 512 + 512];
  u16* lB1a = &B1ls[c0 * 512]; u16* lB1b = &B1ls[c0 * 512 + 512];
  u16* lB3a = &B3ls[c0 * 512]; u16* lB3b = &B3ls[c0 * 512 + 512];

  f32x4 acc1[4][4], acc3[4][4];
#pragma unroll
  for (int i = 0; i < 4; ++i)
#pragma unroll
    for (int j = 0; j < 4; ++j) { acc1[i][j] = (f32x4)0.f; acc3[i][j] = (f32x4)0.f; }

  for (int kt = 0; kt < K / 32; ++kt) {
    __syncthreads();  // all waves done reading LDS of previous step
    const int ko = kt * 32;
    GL16(pA0 + ko, lA0);
    GL16(pA1 + ko, lA1);
    GL16(pB1a + ko, lB1a);
    GL16(pB1b + ko, lB1b);
    GL16(pB3a + ko, lB3a);
    GL16(pB3b + ko, lB3b);
    __syncthreads();  // compiler drains vmcnt before barrier -> LDS valid
    bf16x8 af[4], b1f[4], b3f[4];
#pragma unroll
    for (int i = 0; i < 4; ++i) {
      af[i] = *(const bf16x8*)&Als[(wm * 64 + i * 16 + lo) * 32 + hi * 8];
      b1f[i] = *(const bf16x8*)&B1ls[(wn * 64 + i * 16 + lo) * 32 + hi * 8];
      b3f[i] = *(const bf16x8*)&B3ls[(wn * 64 + i * 16 + lo) * 32 + hi * 8];
    }
#pragma unroll
    for (int i = 0; i < 4; ++i)
#pragma unroll
      for (int j = 0; j < 4; ++j) {
        acc1[i][j] = __builtin_amdgcn_mfma_f32_16x16x32_bf16(af[i], b1f[j], acc1[i][j], 0, 0, 0);
        acc3[i][j] = __builtin_amdgcn_mfma_f32_16x16x32_bf16(af[i], b3f[j], acc3[i][j], 0, 0, 0);
      }
  }

  const size_t orow0 = (counts ? (size_t)e * CAP : 0) + m_base;
#pragma unroll
  for (int i = 0; i < 4; ++i) {
#pragma unroll
    for (int r = 0; r < 4; ++r) {
      int rl = wm * 64 + i * 16 + hi * 4 + r;
      if (m_base + rl < n_e) {
        u16* orow = Hout + (orow0 + rl) * (size_t)N + n_base;
#pragma unroll
        for (int j = 0; j < 4; ++j) {
          float s1 = acc1[i][j][r], s3 = acc3[i][j][r];
          float hv = s1 / (1.f + __expf(-s1)) * s3;
          orow[wn * 64 + j * 16 + lo] = f2bf(hv);
        }
      }
    }
  }
}

// ---------------- GEMM2: Out = A@W2 ; A rows direct ----------------
// A: [e*CAP|M][2048] bf16. B: [e][1024][2048] bf16 ([N][K]). Out: bf16 Y or fp32 final
__launch_bounds__(256, 2)
__global__ void gemm2_k(const u16* __restrict__ Ag, const u16* __restrict__ Bg,
                        void* __restrict__ Outv, const int* __restrict__ counts, int Mfix,
                        int outFloat) {
  constexpr int K = DFF;
  constexpr int N = DM;
  const int e = blockIdx.z;
  int n_e = counts ? counts[e] : Mfix;
  if (counts && n_e > CAP) n_e = CAP;  // capacity clamp ONLY for routed experts
  const int m_base = blockIdx.x * 128;
  if (m_base >= n_e) return;
  const int n_base = blockIdx.y * 128;
  const u16* A = Ag + (counts ? (size_t)e * CAP * K : 0);
  const u16* B = Bg + (counts ? (size_t)e * N * K : 0);

  __shared__ __align__(16) u16 Als[128 * 32];
  __shared__ __align__(16) u16 Bls[128 * 32];

  const int tid = threadIdx.x;
  const int lane = tid & 63;
  const int w = tid >> 6;
  const int wm = w >> 1, wn = w & 1;
  const int lo = lane & 15, hi = lane >> 4;

  const int c0 = 2 * w;
  const int r0 = c0 * 16 + (lane >> 2);
  const int r1 = r0 + 16;
  const int sg = lane & 3;

  const u16* pA0 = A + (size_t)(m_base + r0) * K + sg * 8;
  const u16* pA1 = A + (size_t)(m_base + r1) * K + sg * 8;
  const u16* pB0 = B + (size_t)(n_base + r0) * K + sg * 8;
  const u16* pB1 = B + (size_t)(n_base + r1) * K + sg * 8;
  u16* lA0 = &Als[c0 * 512]; u16* lA1 = &Als[c0 * 512 + 512];
  u16* lB0 = &Bls[c0 * 512]; u16* lB1 = &Bls[c0 * 512 + 512];

  f32x4 acc[4][4];
#pragma unroll
  for (int i = 0; i < 4; ++i)
#pragma unroll
    for (int j = 0; j < 4; ++j) acc[i][j] = (f32x4)0.f;

  for (int kt = 0; kt < K / 32; ++kt) {
    __syncthreads();
    const int ko = kt * 32;
    GL16(pA0 + ko, lA0);
    GL16(pA1 + ko, lA1);
    GL16(pB0 + ko, lB0);
    GL16(pB1 + ko, lB1);
    __syncthreads();
    bf16x8 af[4], bfg[4];
#pragma unroll
    for (int i = 0; i < 4; ++i) {
      af[i] = *(const bf16x8*)&Als[(wm * 64 + i * 16 + lo) * 32 + hi * 8];
      bfg[i] = *(const bf16x8*)&Bls[(wn * 64 + i * 16 + lo) * 32 + hi * 8];
    }
#pragma unroll
    for (int i = 0; i < 4; ++i)
#pragma unroll
      for (int j = 0; j < 4; ++j)
        acc[i][j] = __builtin_amdgcn_mfma_f32_16x16x32_bf16(af[i], bfg[j], acc[i][j], 0, 0, 0);
  }

#pragma unroll
  for (int i = 0; i < 4; ++i) {
#pragma unroll
    for (int r = 0; r < 4; ++r) {
      int rl = wm * 64 + i * 16 + hi * 4 + r;
      if (m_base + rl < n_e) {
        if (outFloat) {
          float* orow = (float*)Outv + (size_t)(m_base + rl) * N + n_base;
#pragma unroll
          for (int j = 0; j < 4; ++j) orow[wn * 64 + j * 16 + lo] = acc[i][j][r];
        } else {
          u16* orow = (u16*)Outv + ((size_t)e * CAP + m_base + rl) * N + n_base;
#pragma unroll
          for (int j = 0; j < 4; ++j) orow[wn * 64 + j * 16 + lo] = f2bf(acc[i][j][r]);
        }
      }
    }
  }
}

// ---------------- combine: xs[t] = g0*Y[e0][s0] + g1*Y[e1][s1] (bf16) ----------------
__global__ void combine_k(const u16* __restrict__ Y, const int* __restrict__ tok_e,
                          const int* __restrict__ tok_slot, const float* __restrict__ tok_gate,
                          u16* __restrict__ xs) {
  int u = blockIdx.x * 256 + threadIdx.x;
  int t = u >> 7;
  int seg = (u & 127) * 8;
  int e0 = tok_e[t * 2 + 0], e1 = tok_e[t * 2 + 1];
  int s0 = tok_slot[t * 2 + 0], s1 = tok_slot[t * 2 + 1];
  float g0 = tok_gate[t * 2 + 0], g1 = tok_gate[t * 2 + 1];
  u16x8 y0 = *(const u16x8*)(Y + ((size_t)e0 * CAP + s0) * DM + seg);
  u16x8 y1 = *(const u16x8*)(Y + ((size_t)e1 * CAP + s1) * DM + seg);
  u16x8 o;
#pragma unroll
  for (int j = 0; j < 8; ++j) o[j] = f2bf(g0 * bf2f(y0[j]) + g1 * bf2f(y1[j]));
  *(u16x8*)(xs + (size_t)t * DM + seg) = o;
}

// ---------------- host ----------------
extern "C" void kernel_launch(void* const* d_in, const int* in_sizes, int n_in, void* d_out,
                              int out_size, void* d_ws, size_t ws_size, hipStream_t stream) {
  const float* x = (const float*)d_in[0];
  const float* Wr = (const float*)d_in[1];
  const float* W1 = (const float*)d_in[2];
  const float* W2 = (const float*)d_in[3];
  const float* W3 = (const float*)d_in[4];
  const float* Ws1 = (const float*)d_in[5];
  const float* Ws2 = (const float*)d_in[6];
  const float* Ws3 = (const float*)d_in[7];
  float* out = (float*)d_out;
  (void)in_sizes; (void)n_in; (void)out_size; (void)ws_size;

  char* ws = (char*)d_ws;
  size_t o = 0;
  auto alloc = [&](size_t b) {
    void* p = ws + o;
    o = (o + b + 255) & ~(size_t)255;
    return p;
  };
  int* counters = (int*)alloc(NE * 4);
  int* tok_e = (int*)alloc(TOKENS * 2 * 4);
  int* tok_slot = (int*)alloc(TOKENS * 2 * 4);
  float* tok_gate = (float*)alloc(TOKENS * 2 * 4);
  float* tok_probs = (float*)alloc(TOKENS * NE * 4);
  float* tok_lse = (float*)alloc(TOKENS * 4);
  int* tok_list = (int*)alloc(NE * CAP * 4);
  u16* xb = (u16*)alloc((size_t)TOKENS * DM * 2);
  u16* W1t = (u16*)alloc((size_t)NE * DFF * DM * 2);
  u16* W3t = (u16*)alloc((size_t)NE * DFF * DM * 2);
  u16* W2t = (u16*)alloc((size_t)NE * DM * DFF * 2);
  u16* Ws1t = (u16*)alloc((size_t)DFF * DM * 2);
  u16* Ws3t = (u16*)alloc((size_t)DFF * DM * 2);
  u16* Ws2t = (u16*)alloc((size_t)DM * DFF * 2);
  u16* H = (u16*)alloc((size_t)NE * CAP * DFF * 2);
  u16* Y = (u16*)alloc((size_t)NE * CAP * DM * 2);
  u16* xs = (u16*)alloc((size_t)TOKENS * DM * 2);
  u16* Hs = (u16*)alloc((size_t)TOKENS * DFF * 2);

  zero_k<<<1, 64, 0, stream>>>(counters);
  conv_k<<<TOKENS * DM / 4 / 256, 256, 0, stream>>>(x, xb, TOKENS * DM / 4);
  tconv_k<<<dim3(DM / 64, DFF / 64, NE), 256, 0, stream>>>(W1, W1t, DM, DFF);
  tconv_k<<<dim3(DM / 64, DFF / 64, NE), 256, 0, stream>>>(W3, W3t, DM, DFF);
  tconv_k<<<dim3(DFF / 64, DM / 64, NE), 256, 0, stream>>>(W2, W2t, DFF, DM);
  tconv_k<<<dim3(DM / 64, DFF / 64, 1), 256, 0, stream>>>(Ws1, Ws1t, DM, DFF);
  tconv_k<<<dim3(DM / 64, DFF / 64, 1), 256, 0, stream>>>(Ws3, Ws3t, DM, DFF);
  tconv_k<<<dim3(DFF / 64, DM / 64, 1), 256, 0, stream>>>(Ws2, Ws2t, DFF, DM);
  router_k<<<TOKENS, 64, 0, stream>>>(x, Wr, counters, tok_list, tok_e, tok_slot, tok_gate,
                                      tok_probs, tok_lse);
  finalize_k<<<1, 256, 0, stream>>>(tok_probs, tok_lse, counters, out + (size_t)TOKENS * DM);
  gemm1_k<<<dim3(CAP / 128, DFF / 128, NE), 256, 0, stream>>>(xb, W1t, W3t, H, tok_list,
                                                              counters, 0);
  gemm2_k<<<dim3(CAP / 128, DM / 128, NE), 256, 0, stream>>>(H, W2t, (void*)Y, counters, 0, 0);
  combine_k<<<TOKENS * DM / 8 / 256, 256, 0, stream>>>(Y, tok_e, tok_slot, tok_gate, xs);
  gemm1_k<<<dim3(TOKENS / 128, DFF / 128, 1), 256, 0, stream>>>(xs, Ws1t, Ws3t, Hs, nullptr,
                                                                nullptr, TOKENS);
  gemm2_k<<<dim3(TOKENS / 128, DM / 128, 1), 256, 0, stream>>>(Hs, Ws2t, (void*)out, nullptr,
                                                               TOKENS, 1);
}

// Round 6
// 617.553 us; speedup vs baseline: 1.1425x; 1.1425x over previous
//
#include <hip/hip_runtime.h>

#define TOKENS 4096
#define DM 1024
#define DFF 2048
#define NE 8
#define CAP 2048

typedef unsigned short u16;
typedef __attribute__((ext_vector_type(8))) __bf16 bf16x8;
typedef __attribute__((ext_vector_type(8))) unsigned short u16x8;
typedef __attribute__((ext_vector_type(4))) float f32x4;

// async global->LDS, 16B per lane; LDS dest must be wave-uniform base (HW adds lane*16)
#define GL16(g, l)                                                                        \
  __builtin_amdgcn_global_load_lds((const __attribute__((address_space(1))) void*)(g),    \
                                   (__attribute__((address_space(3))) void*)(l), 16, 0, 0)

__device__ __forceinline__ u16 f2bf(float f) {
  unsigned int u = __builtin_bit_cast(unsigned int, f);
  unsigned int r = (u + 0x7FFFu + ((u >> 16) & 1u)) >> 16;
  return (u16)r;
}
__device__ __forceinline__ float bf2f(u16 h) {
  unsigned int u = ((unsigned int)h) << 16;
  return __builtin_bit_cast(float, u);
}

// ---------------- init ----------------
__global__ void zero_k(int* counters) {
  if (threadIdx.x < NE) counters[threadIdx.x] = 0;
}

// ---------------- fp32 -> bf16 convert (no transpose) ----------------
__global__ void conv_k(const float* __restrict__ src, u16* __restrict__ dst, int n4) {
  int i = blockIdx.x * 256 + threadIdx.x;
  if (i >= n4) return;
  float4 v = ((const float4*)src)[i];
  ushort4 ov = make_ushort4(f2bf(v.x), f2bf(v.y), f2bf(v.z), f2bf(v.w));
  ((ushort4*)dst)[i] = ov;
}

// ------------- fp32 [z][K][N] -> bf16 [z][N][K] transpose-convert -------------
__global__ void tconv_k(const float* __restrict__ src, u16* __restrict__ dst, int K, int N) {
  __shared__ u16 tile[64][68];
  const int k0 = blockIdx.x * 64;
  const int n0 = blockIdx.y * 64;
  const size_t zoff = (size_t)blockIdx.z * K * N;
  const float* s = src + zoff;
  u16* d = dst + zoff;
  const int tid = threadIdx.x;
#pragma unroll
  for (int p = 0; p < 4; ++p) {
    int idx = p * 256 + tid;
    int kr = idx >> 4;
    int nc = (idx & 15) * 4;
    float4 v = *(const float4*)(s + (size_t)(k0 + kr) * N + (n0 + nc));
    tile[kr][nc + 0] = f2bf(v.x);
    tile[kr][nc + 1] = f2bf(v.y);
    tile[kr][nc + 2] = f2bf(v.z);
    tile[kr][nc + 3] = f2bf(v.w);
  }
  __syncthreads();
#pragma unroll
  for (int p = 0; p < 4; ++p) {
    int idx = p * 256 + tid;
    int nr = idx >> 4;
    int kc = (idx & 15) * 4;
    ushort4 ov = make_ushort4(tile[kc + 0][nr], tile[kc + 1][nr], tile[kc + 2][nr], tile[kc + 3][nr]);
    *(ushort4*)(d + (size_t)(n0 + nr) * K + (k0 + kc)) = ov;
  }
}

// ---------------- router: logits, probs, lse, top-2, slot assignment ----------------
__global__ void router_k(const float* __restrict__ x, const float* __restrict__ Wr,
                         int* __restrict__ counters, int* __restrict__ tok_list,
                         int* __restrict__ tok_e, int* __restrict__ tok_slot,
                         float* __restrict__ tok_gate, float* __restrict__ tok_probs,
                         float* __restrict__ tok_lse) {
  const int t = blockIdx.x;
  const int l = threadIdx.x;
  float acc[NE];
#pragma unroll
  for (int e = 0; e < NE; ++e) acc[e] = 0.f;
  const float* xr = x + (size_t)t * DM;
#pragma unroll
  for (int it = 0; it < DM / 64; ++it) {
    int d = it * 64 + l;
    float xv = xr[d];
    const float4* wr = (const float4*)(Wr + (size_t)d * NE);
    float4 w0 = wr[0], w1 = wr[1];
    acc[0] += xv * w0.x; acc[1] += xv * w0.y; acc[2] += xv * w0.z; acc[3] += xv * w0.w;
    acc[4] += xv * w1.x; acc[5] += xv * w1.y; acc[6] += xv * w1.z; acc[7] += xv * w1.w;
  }
#pragma unroll
  for (int off = 32; off >= 1; off >>= 1) {
#pragma unroll
    for (int e = 0; e < NE; ++e) acc[e] += __shfl_xor(acc[e], off, 64);
  }
  if (l == 0) {
    float m = acc[0];
#pragma unroll
    for (int e = 1; e < NE; ++e) m = fmaxf(m, acc[e]);
    float ex[NE], s = 0.f;
#pragma unroll
    for (int e = 0; e < NE; ++e) { ex[e] = expf(acc[e] - m); s += ex[e]; }
    float inv = 1.f / s;
#pragma unroll
    for (int e = 0; e < NE; ++e) tok_probs[t * NE + e] = ex[e] * inv;
    tok_lse[t] = m + logf(s);
    // top-2 (ties -> lowest index, matching jax.lax.top_k)
    int i0 = 0; float l0 = acc[0];
#pragma unroll
    for (int e = 1; e < NE; ++e) if (acc[e] > l0) { l0 = acc[e]; i0 = e; }
    int i1 = -1; float l1 = -3.0e38f;
#pragma unroll
    for (int e = 0; e < NE; ++e) if (e != i0 && acc[e] > l1) { l1 = acc[e]; i1 = e; }
    float e1 = expf(l1 - l0);
    float g0 = 1.f / (1.f + e1);
    float g1 = e1 / (1.f + e1);
    int p0 = atomicAdd(&counters[i0], 1);
    int p1 = atomicAdd(&counters[i1], 1);
    if (p0 < CAP) tok_list[i0 * CAP + p0] = t;
    if (p1 < CAP) tok_list[i1 * CAP + p1] = t;
    tok_e[t * 2 + 0] = i0; tok_e[t * 2 + 1] = i1;
    tok_slot[t * 2 + 0] = p0; tok_slot[t * 2 + 1] = p1;
    tok_gate[t * 2 + 0] = g0; tok_gate[t * 2 + 1] = g1;
  }
}

// ---------------- loss finalize ----------------
__global__ void finalize_k(const float* __restrict__ tok_probs, const float* __restrict__ tok_lse,
                           const int* __restrict__ counters, float* __restrict__ tail) {
  __shared__ float s_p[NE];
  __shared__ float s_z;
  const int tid = threadIdx.x;
  if (tid == 0) s_z = 0.f;
  if (tid < NE) s_p[tid] = 0.f;
  __syncthreads();
  float lp[NE] = {0, 0, 0, 0, 0, 0, 0, 0};
  float lz = 0.f;
  for (int t = tid; t < TOKENS; t += 256) {
    float l = tok_lse[t];
    lz += l * l;
#pragma unroll
    for (int e = 0; e < NE; ++e) lp[e] += tok_probs[t * NE + e];
  }
#pragma unroll
  for (int off = 32; off >= 1; off >>= 1) {
    lz += __shfl_xor(lz, off, 64);
#pragma unroll
    for (int e = 0; e < NE; ++e) lp[e] += __shfl_xor(lp[e], off, 64);
  }
  if ((tid & 63) == 0) {
    atomicAdd(&s_z, lz);
    for (int e = 0; e < NE; ++e) atomicAdd(&s_p[e], lp[e]);
  }
  __syncthreads();
  if (tid == 0) {
    float z = s_z / (float)TOKENS;
    float lb = 0.f;
    for (int e = 0; e < NE; ++e) {
      float f = (float)counters[e] / (float)(TOKENS * 2);
      float p = s_p[e] / (float)TOKENS;
      lb += p * f;
      tail[e] = f;
    }
    lb *= (float)NE;
    tail[8] = z;
    tail[9] = z * 0.001f;
    tail[10] = lb;
    tail[11] = lb * 0.1f;
  }
}

// ---------------- GEMM1: H = silu(A@W1) * (A@W3);  A gathered rows of xb ----------------
// 1D swizzled grid; 2-phase double-buffered global_load_lds prefetch (T3 minimum recipe).
__launch_bounds__(256, 2)
__global__ void gemm1_k(const u16* __restrict__ A, const u16* __restrict__ B1g,
                        const u16* __restrict__ B3g, u16* __restrict__ Hout,
                        const int* __restrict__ tok_list, const int* __restrict__ counts,
                        int Mfix, int MBg, int NBg) {
  constexpr int K = DM;
  constexpr int N = DFF;
  constexpr int NT = K / 32;
  // --- bijective XCD swizzle (nwg % 8 == 0), m varies fastest within chunk ---
  const int nwg = gridDim.x;
  const int cpx = nwg >> 3;
  const int wg = (blockIdx.x & 7) * cpx + (blockIdx.x >> 3);
  const int per = MBg * NBg;
  const int e = wg / per;
  const int rem = wg - e * per;
  const int m_blk = rem % MBg;
  const int n_blk = rem / MBg;
  int n_e = counts ? counts[e] : Mfix;
  if (counts && n_e > CAP) n_e = CAP;  // capacity clamp ONLY for routed experts
  const int m_base = m_blk * 128;
  if (m_base >= n_e) return;
  const int n_base = n_blk * 128;
  const size_t bstride = counts ? (size_t)N * K : 0;
  const u16* B1 = B1g + (size_t)e * bstride;
  const u16* B3 = B3g + (size_t)e * bstride;

  __shared__ __align__(16) u16 Als[2][128 * 32];
  __shared__ __align__(16) u16 B1ls[2][128 * 32];
  __shared__ __align__(16) u16 B3ls[2][128 * 32];

  const int tid = threadIdx.x;
  const int lane = tid & 63;
  const int w = tid >> 6;
  const int wm = w >> 1, wn = w & 1;
  const int lo = lane & 15, hi = lane >> 4;

  // ---- staging geometry: tile [128][32]u16 = 8 chunks of 1024B; wave w -> chunks {2w,2w+1}
  const int c0 = 2 * w;
  const int r0 = c0 * 16 + (lane >> 2);
  const int r1 = r0 + 16;
  const int sg = lane & 3;

  size_t ar0, ar1;
  if (tok_list) {
    int g0i = m_base + r0; if (g0i >= n_e) g0i = n_e - 1;
    int g1i = m_base + r1; if (g1i >= n_e) g1i = n_e - 1;
    ar0 = (size_t)tok_list[e * CAP + g0i];
    ar1 = (size_t)tok_list[e * CAP + g1i];
  } else {
    ar0 = (size_t)(m_base + r0);
    ar1 = (size_t)(m_base + r1);
  }
  const u16* pA0 = A + ar0 * (size_t)K + sg * 8;
  const u16* pA1 = A + ar1 * (size_t)K + sg * 8;
  const u16* pB1a = B1 + (size_t)(n_base + r0) * K + sg * 8;
  const u16* pB1b = B1 + (size_t)(n_base + r1) * K + sg * 8;
  const u16* pB3a = B3 + (size_t)(n_base + r0) * K + sg * 8;
  const u16* pB3b = B3 + (size_t)(n_base + r1) * K + sg * 8;

  f32x4 acc1[4][4], acc3[4][4];
#pragma unroll
  for (int i = 0; i < 4; ++i)
#pragma unroll
    for (int j = 0; j < 4; ++j) { acc1[i][j] = (f32x4)0.f; acc3[i][j] = (f32x4)0.f; }

  auto compute = [&](const u16* rA, const u16* rB1, const u16* rB3) {
    bf16x8 af[4], b1f[4], b3f[4];
#pragma unroll
    for (int i = 0; i < 4; ++i) {
      af[i] = *(const bf16x8*)&rA[(wm * 64 + i * 16 + lo) * 32 + hi * 8];
      b1f[i] = *(const bf16x8*)&rB1[(wn * 64 + i * 16 + lo) * 32 + hi * 8];
      b3f[i] = *(const bf16x8*)&rB3[(wn * 64 + i * 16 + lo) * 32 + hi * 8];
    }
#pragma unroll
    for (int i = 0; i < 4; ++i)
#pragma unroll
      for (int j = 0; j < 4; ++j) {
        acc1[i][j] = __builtin_amdgcn_mfma_f32_16x16x32_bf16(af[i], b1f[j], acc1[i][j], 0, 0, 0);
        acc3[i][j] = __builtin_amdgcn_mfma_f32_16x16x32_bf16(af[i], b3f[j], acc3[i][j], 0, 0, 0);
      }
  };

  // prologue: stage tile 0 into buf 0
  GL16(pA0, &Als[0][c0 * 512]);  GL16(pA1, &Als[0][c0 * 512 + 512]);
  GL16(pB1a, &B1ls[0][c0 * 512]); GL16(pB1b, &B1ls[0][c0 * 512 + 512]);
  GL16(pB3a, &B3ls[0][c0 * 512]); GL16(pB3b, &B3ls[0][c0 * 512 + 512]);
  __syncthreads();
  int cur = 0;
  for (int kt = 0; kt < NT - 1; ++kt) {
    const int ko = (kt + 1) * 32;
    u16* sA = cur ? &Als[0][c0 * 512] : &Als[1][c0 * 512];
    u16* sB1 = cur ? &B1ls[0][c0 * 512] : &B1ls[1][c0 * 512];
    u16* sB3 = cur ? &B3ls[0][c0 * 512] : &B3ls[1][c0 * 512];
    GL16(pA0 + ko, sA);  GL16(pA1 + ko, sA + 512);
    GL16(pB1a + ko, sB1); GL16(pB1b + ko, sB1 + 512);
    GL16(pB3a + ko, sB3); GL16(pB3b + ko, sB3 + 512);
    compute(cur ? &Als[1][0] : &Als[0][0],
            cur ? &B1ls[1][0] : &B1ls[0][0],
            cur ? &B3ls[1][0] : &B3ls[0][0]);
    __syncthreads();  // drains vmcnt (stage done) after compute -> latency hidden
    cur ^= 1;
  }
  compute(cur ? &Als[1][0] : &Als[0][0],
          cur ? &B1ls[1][0] : &B1ls[0][0],
          cur ? &B3ls[1][0] : &B3ls[0][0]);

  const size_t orow0 = (counts ? (size_t)e * CAP : 0) + m_base;
#pragma unroll
  for (int i = 0; i < 4; ++i) {
#pragma unroll
    for (int r = 0; r < 4; ++r) {
      int rl = wm * 64 + i * 16 + hi * 4 + r;
      if (m_base + rl < n_e) {
        u16* orow = Hout + (orow0 + rl) * (size_t)N + n_base;
#pragma unroll
        for (int j = 0; j < 4; ++j) {
          float s1 = acc1[i][j][r], s3 = acc3[i][j][r];
          float hv = s1 / (1.f + __expf(-s1)) * s3;
          orow[wn * 64 + j * 16 + lo] = f2bf(hv);
        }
      }
    }
  }
}

// ---------------- GEMM2: Out = A@W2 ; A rows direct ----------------
__launch_bounds__(256, 2)
__global__ void gemm2_k(const u16* __restrict__ Ag, const u16* __restrict__ Bg,
                        void* __restrict__ Outv, const int* __restrict__ counts, int Mfix,
                        int outFloat, int MBg, int NBg) {
  constexpr int K = DFF;
  constexpr int N = DM;
  constexpr int NT = K / 32;
  const int nwg = gridDim.x;
  const int cpx = nwg >> 3;
  const int wg = (blockIdx.x & 7) * cpx + (blockIdx.x >> 3);
  const int per = MBg * NBg;
  const int e = wg / per;
  const int rem = wg - e * per;
  const int m_blk = rem % MBg;
  const int n_blk = rem / MBg;
  int n_e = counts ? counts[e] : Mfix;
  if (counts && n_e > CAP) n_e = CAP;  // capacity clamp ONLY for routed experts
  const int m_base = m_blk * 128;
  if (m_base >= n_e) return;
  const int n_base = n_blk * 128;
  const u16* A = Ag + (counts ? (size_t)e * CAP * K : 0);
  const u16* B = Bg + (counts ? (size_t)e * N * K : 0);

  __shared__ __align__(16) u16 Als[2][128 * 32];
  __shared__ __align__(16) u16 Bls[2][128 * 32];

  const int tid = threadIdx.x;
  const int lane = tid & 63;
  const int w = tid >> 6;
  const int wm = w >> 1, wn = w & 1;
  const int lo = lane & 15, hi = lane >> 4;

  const int c0 = 2 * w;
  const int r0 = c0 * 16 + (lane >> 2);
  const int r1 = r0 + 16;
  const int sg = lane & 3;

  const u16* pA0 = A + (size_t)(m_base + r0) * K + sg * 8;
  const u16* pA1 = A + (size_t)(m_base + r1) * K + sg * 8;
  const u16* pB0 = B + (size_t)(n_base + r0) * K + sg * 8;
  const u16* pB1 = B + (size_t)(n_base + r1) * K + sg * 8;

  f32x4 acc[4][4];
#pragma unroll
  for (int i = 0; i < 4; ++i)
#pragma unroll
    for (int j = 0; j < 4; ++j) acc[i][j] = (f32x4)0.f;

  auto compute = [&](const u16* rA, const u16* rB) {
    bf16x8 af[4], bfg[4];
#pragma unroll
    for (int i = 0; i < 4; ++i) {
      af[i] = *(const bf16x8*)&rA[(wm * 64 + i * 16 + lo) * 32 + hi * 8];
      bfg[i] = *(const bf16x8*)&rB[(wn * 64 + i * 16 + lo) * 32 + hi * 8];
    }
#pragma unroll
    for (int i = 0; i < 4; ++i)
#pragma unroll
      for (int j = 0; j < 4; ++j)
        acc[i][j] = __builtin_amdgcn_mfma_f32_16x16x32_bf16(af[i], bfg[j], acc[i][j], 0, 0, 0);
  };

  GL16(pA0, &Als[0][c0 * 512]); GL16(pA1, &Als[0][c0 * 512 + 512]);
  GL16(pB0, &Bls[0][c0 * 512]); GL16(pB1, &Bls[0][c0 * 512 + 512]);
  __syncthreads();
  int cur = 0;
  for (int kt = 0; kt < NT - 1; ++kt) {
    const int ko = (kt + 1) * 32;
    u16* sA = cur ? &Als[0][c0 * 512] : &Als[1][c0 * 512];
    u16* sB = cur ? &Bls[0][c0 * 512] : &Bls[1][c0 * 512];
    GL16(pA0 + ko, sA); GL16(pA1 + ko, sA + 512);
    GL16(pB0 + ko, sB); GL16(pB1 + ko, sB + 512);
    compute(cur ? &Als[1][0] : &Als[0][0], cur ? &Bls[1][0] : &Bls[0][0]);
    __syncthreads();
    cur ^= 1;
  }
  compute(cur ? &Als[1][0] : &Als[0][0], cur ? &Bls[1][0] : &Bls[0][0]);

#pragma unroll
  for (int i = 0; i < 4; ++i) {
#pragma unroll
    for (int r = 0; r < 4; ++r) {
      int rl = wm * 64 + i * 16 + hi * 4 + r;
      if (m_base + rl < n_e) {
        if (outFloat) {
          float* orow = (float*)Outv + (size_t)(m_base + rl) * N + n_base;
#pragma unroll
          for (int j = 0; j < 4; ++j) orow[wn * 64 + j * 16 + lo] = acc[i][j][r];
        } else {
          u16* orow = (u16*)Outv + ((size_t)e * CAP + m_base + rl) * N + n_base;
#pragma unroll
          for (int j = 0; j < 4; ++j) orow[wn * 64 + j * 16 + lo] = f2bf(acc[i][j][r]);
        }
      }
    }
  }
}

// ---------------- combine: xs[t] = g0*Y[e0][s0] + g1*Y[e1][s1] (bf16) ----------------
__global__ void combine_k(const u16* __restrict__ Y, const int* __restrict__ tok_e,
                          const int* __restrict__ tok_slot, const float* __restrict__ tok_gate,
                          u16* __restrict__ xs) {
  int u = blockIdx.x * 256 + threadIdx.x;
  int t = u >> 7;
  int seg = (u & 127) * 8;
  int e0 = tok_e[t * 2 + 0], e1 = tok_e[t * 2 + 1];
  int s0 = tok_slot[t * 2 + 0], s1 = tok_slot[t * 2 + 1];
  float g0 = tok_gate[t * 2 + 0], g1 = tok_gate[t * 2 + 1];
  u16x8 y0 = *(const u16x8*)(Y + ((size_t)e0 * CAP + s0) * DM + seg);
  u16x8 y1 = *(const u16x8*)(Y + ((size_t)e1 * CAP + s1) * DM + seg);
  u16x8 o;
#pragma unroll
  for (int j = 0; j < 8; ++j) o[j] = f2bf(g0 * bf2f(y0[j]) + g1 * bf2f(y1[j]));
  *(u16x8*)(xs + (size_t)t * DM + seg) = o;
}

// ---------------- host ----------------
extern "C" void kernel_launch(void* const* d_in, const int* in_sizes, int n_in, void* d_out,
                              int out_size, void* d_ws, size_t ws_size, hipStream_t stream) {
  const float* x = (const float*)d_in[0];
  const float* Wr = (const float*)d_in[1];
  const float* W1 = (const float*)d_in[2];
  const float* W2 = (const float*)d_in[3];
  const float* W3 = (const float*)d_in[4];
  const float* Ws1 = (const float*)d_in[5];
  const float* Ws2 = (const float*)d_in[6];
  const float* Ws3 = (const float*)d_in[7];
  float* out = (float*)d_out;
  (void)in_sizes; (void)n_in; (void)out_size; (void)ws_size;

  char* ws = (char*)d_ws;
  size_t o = 0;
  auto alloc = [&](size_t b) {
    void* p = ws + o;
    o = (o + b + 255) & ~(size_t)255;
    return p;
  };
  int* counters = (int*)alloc(NE * 4);
  int* tok_e = (int*)alloc(TOKENS * 2 * 4);
  int* tok_slot = (int*)alloc(TOKENS * 2 * 4);
  float* tok_gate = (float*)alloc(TOKENS * 2 * 4);
  float* tok_probs = (float*)alloc(TOKENS * NE * 4);
  float* tok_lse = (float*)alloc(TOKENS * 4);
  int* tok_list = (int*)alloc(NE * CAP * 4);
  u16* xb = (u16*)alloc((size_t)TOKENS * DM * 2);
  u16* W1t = (u16*)alloc((size_t)NE * DFF * DM * 2);
  u16* W3t = (u16*)alloc((size_t)NE * DFF * DM * 2);
  u16* W2t = (u16*)alloc((size_t)NE * DM * DFF * 2);
  u16* Ws1t = (u16*)alloc((size_t)DFF * DM * 2);
  u16* Ws3t = (u16*)alloc((size_t)DFF * DM * 2);
  u16* Ws2t = (u16*)alloc((size_t)DM * DFF * 2);
  u16* H = (u16*)alloc((size_t)NE * CAP * DFF * 2);
  u16* Y = (u16*)alloc((size_t)NE * CAP * DM * 2);
  u16* xs = (u16*)alloc((size_t)TOKENS * DM * 2);
  u16* Hs = (u16*)alloc((size_t)TOKENS * DFF * 2);

  zero_k<<<1, 64, 0, stream>>>(counters);
  conv_k<<<TOKENS * DM / 4 / 256, 256, 0, stream>>>(x, xb, TOKENS * DM / 4);
  tconv_k<<<dim3(DM / 64, DFF / 64, NE), 256, 0, stream>>>(W1, W1t, DM, DFF);
  tconv_k<<<dim3(DM / 64, DFF / 64, NE), 256, 0, stream>>>(W3, W3t, DM, DFF);
  tconv_k<<<dim3(DFF / 64, DM / 64, NE), 256, 0, stream>>>(W2, W2t, DFF, DM);
  tconv_k<<<dim3(DM / 64, DFF / 64, 1), 256, 0, stream>>>(Ws1, Ws1t, DM, DFF);
  tconv_k<<<dim3(DM / 64, DFF / 64, 1), 256, 0, stream>>>(Ws3, Ws3t, DM, DFF);
  tconv_k<<<dim3(DFF / 64, DM / 64, 1), 256, 0, stream>>>(Ws2, Ws2t, DFF, DM);
  router_k<<<TOKENS, 64, 0, stream>>>(x, Wr, counters, tok_list, tok_e, tok_slot, tok_gate,
                                      tok_probs, tok_lse);
  finalize_k<<<1, 256, 0, stream>>>(tok_probs, tok_lse, counters, out + (size_t)TOKENS * DM);
  // expert GEMM1: 16 m-blk x 16 n-blk x 8 experts = 2048 blocks (1D, XCD-swizzled)
  gemm1_k<<<16 * 16 * NE, 256, 0, stream>>>(xb, W1t, W3t, H, tok_list, counters, 0, 16, 16);
  // expert GEMM2: 16 x 8 x 8 = 1024 blocks
  gemm2_k<<<16 * 8 * NE, 256, 0, stream>>>(H, W2t, (void*)Y, counters, 0, 0, 16, 8);
  combine_k<<<TOKENS * DM / 8 / 256, 256, 0, stream>>>(Y, tok_e, tok_slot, tok_gate, xs);
  // shared GEMM1: 32 x 16 = 512 blocks
  gemm1_k<<<32 * 16, 256, 0, stream>>>(xs, Ws1t, Ws3t, Hs, nullptr, nullptr, TOKENS, 32, 16);
  // shared GEMM2: 32 x 8 = 256 blocks
  gemm2_k<<<32 * 8, 256, 0, stream>>>(Hs, Ws2t, (void*)out, nullptr, TOKENS, 1, 32, 8);
}

// Round 7
// 615.314 us; speedup vs baseline: 1.1467x; 1.0036x over previous
//
#include <hip/hip_runtime.h>

#define TOKENS 4096
#define DM 1024
#define DFF 2048
#define NE 8
#define CAP 2048

typedef unsigned short u16;
typedef __attribute__((ext_vector_type(8))) __bf16 bf16x8;
typedef __attribute__((ext_vector_type(8))) unsigned short u16x8;
typedef __attribute__((ext_vector_type(4))) float f32x4;

// async global->LDS, 16B per lane; LDS dest must be wave-uniform base (HW adds lane*16)
#define GL16(g, l)                                                                        \
  __builtin_amdgcn_global_load_lds((const __attribute__((address_space(1))) void*)(g),    \
                                   (__attribute__((address_space(3))) void*)(l), 16, 0, 0)

__device__ __forceinline__ u16 f2bf(float f) {
  unsigned int u = __builtin_bit_cast(unsigned int, f);
  unsigned int r = (u + 0x7FFFu + ((u >> 16) & 1u)) >> 16;
  return (u16)r;
}
__device__ __forceinline__ float bf2f(u16 h) {
  unsigned int u = ((unsigned int)h) << 16;
  return __builtin_bit_cast(float, u);
}

// ---------------- init ----------------
__global__ void zero_k(int* counters) {
  if (threadIdx.x < NE) counters[threadIdx.x] = 0;
}

// ---------------- fp32 -> bf16 convert (no transpose) ----------------
__global__ void conv_k(const float* __restrict__ src, u16* __restrict__ dst, int n4) {
  int i = blockIdx.x * 256 + threadIdx.x;
  if (i >= n4) return;
  float4 v = ((const float4*)src)[i];
  ushort4 ov = make_ushort4(f2bf(v.x), f2bf(v.y), f2bf(v.z), f2bf(v.w));
  ((ushort4*)dst)[i] = ov;
}

// ------------- fp32 [z][K][N] -> bf16 [z][N][K] transpose-convert -------------
__global__ void tconv_k(const float* __restrict__ src, u16* __restrict__ dst, int K, int N) {
  __shared__ u16 tile[64][68];
  const int k0 = blockIdx.x * 64;
  const int n0 = blockIdx.y * 64;
  const size_t zoff = (size_t)blockIdx.z * K * N;
  const float* s = src + zoff;
  u16* d = dst + zoff;
  const int tid = threadIdx.x;
#pragma unroll
  for (int p = 0; p < 4; ++p) {
    int idx = p * 256 + tid;
    int kr = idx >> 4;
    int nc = (idx & 15) * 4;
    float4 v = *(const float4*)(s + (size_t)(k0 + kr) * N + (n0 + nc));
    tile[kr][nc + 0] = f2bf(v.x);
    tile[kr][nc + 1] = f2bf(v.y);
    tile[kr][nc + 2] = f2bf(v.z);
    tile[kr][nc + 3] = f2bf(v.w);
  }
  __syncthreads();
#pragma unroll
  for (int p = 0; p < 4; ++p) {
    int idx = p * 256 + tid;
    int nr = idx >> 4;
    int kc = (idx & 15) * 4;
    ushort4 ov = make_ushort4(tile[kc + 0][nr], tile[kc + 1][nr], tile[kc + 2][nr], tile[kc + 3][nr]);
    *(ushort4*)(d + (size_t)(n0 + nr) * K + (k0 + kc)) = ov;
  }
}

// ---------------- router: logits, probs, lse, top-2, slot assignment ----------------
__global__ void router_k(const float* __restrict__ x, const float* __restrict__ Wr,
                         int* __restrict__ counters, int* __restrict__ tok_list,
                         int* __restrict__ tok_e, int* __restrict__ tok_slot,
                         float* __restrict__ tok_gate, float* __restrict__ tok_probs,
                         float* __restrict__ tok_lse) {
  const int t = blockIdx.x;
  const int l = threadIdx.x;
  float acc[NE];
#pragma unroll
  for (int e = 0; e < NE; ++e) acc[e] = 0.f;
  const float* xr = x + (size_t)t * DM;
#pragma unroll
  for (int it = 0; it < DM / 64; ++it) {
    int d = it * 64 + l;
    float xv = xr[d];
    const float4* wr = (const float4*)(Wr + (size_t)d * NE);
    float4 w0 = wr[0], w1 = wr[1];
    acc[0] += xv * w0.x; acc[1] += xv * w0.y; acc[2] += xv * w0.z; acc[3] += xv * w0.w;
    acc[4] += xv * w1.x; acc[5] += xv * w1.y; acc[6] += xv * w1.z; acc[7] += xv * w1.w;
  }
#pragma unroll
  for (int off = 32; off >= 1; off >>= 1) {
#pragma unroll
    for (int e = 0; e < NE; ++e) acc[e] += __shfl_xor(acc[e], off, 64);
  }
  if (l == 0) {
    float m = acc[0];
#pragma unroll
    for (int e = 1; e < NE; ++e) m = fmaxf(m, acc[e]);
    float ex[NE], s = 0.f;
#pragma unroll
    for (int e = 0; e < NE; ++e) { ex[e] = expf(acc[e] - m); s += ex[e]; }
    float inv = 1.f / s;
#pragma unroll
    for (int e = 0; e < NE; ++e) tok_probs[t * NE + e] = ex[e] * inv;
    tok_lse[t] = m + logf(s);
    // top-2 (ties -> lowest index, matching jax.lax.top_k)
    int i0 = 0; float l0 = acc[0];
#pragma unroll
    for (int e = 1; e < NE; ++e) if (acc[e] > l0) { l0 = acc[e]; i0 = e; }
    int i1 = -1; float l1 = -3.0e38f;
#pragma unroll
    for (int e = 0; e < NE; ++e) if (e != i0 && acc[e] > l1) { l1 = acc[e]; i1 = e; }
    float e1 = expf(l1 - l0);
    float g0 = 1.f / (1.f + e1);
    float g1 = e1 / (1.f + e1);
    int p0 = atomicAdd(&counters[i0], 1);
    int p1 = atomicAdd(&counters[i1], 1);
    if (p0 < CAP) tok_list[i0 * CAP + p0] = t;
    if (p1 < CAP) tok_list[i1 * CAP + p1] = t;
    tok_e[t * 2 + 0] = i0; tok_e[t * 2 + 1] = i1;
    tok_slot[t * 2 + 0] = p0; tok_slot[t * 2 + 1] = p1;
    tok_gate[t * 2 + 0] = g0; tok_gate[t * 2 + 1] = g1;
  }
}

// ---------------- loss finalize ----------------
__global__ void finalize_k(const float* __restrict__ tok_probs, const float* __restrict__ tok_lse,
                           const int* __restrict__ counters, float* __restrict__ tail) {
  __shared__ float s_p[NE];
  __shared__ float s_z;
  const int tid = threadIdx.x;
  if (tid == 0) s_z = 0.f;
  if (tid < NE) s_p[tid] = 0.f;
  __syncthreads();
  float lp[NE] = {0, 0, 0, 0, 0, 0, 0, 0};
  float lz = 0.f;
  for (int t = tid; t < TOKENS; t += 256) {
    float l = tok_lse[t];
    lz += l * l;
#pragma unroll
    for (int e = 0; e < NE; ++e) lp[e] += tok_probs[t * NE + e];
  }
#pragma unroll
  for (int off = 32; off >= 1; off >>= 1) {
    lz += __shfl_xor(lz, off, 64);
#pragma unroll
    for (int e = 0; e < NE; ++e) lp[e] += __shfl_xor(lp[e], off, 64);
  }
  if ((tid & 63) == 0) {
    atomicAdd(&s_z, lz);
    for (int e = 0; e < NE; ++e) atomicAdd(&s_p[e], lp[e]);
  }
  __syncthreads();
  if (tid == 0) {
    float z = s_z / (float)TOKENS;
    float lb = 0.f;
    for (int e = 0; e < NE; ++e) {
      float f = (float)counters[e] / (float)(TOKENS * 2);
      float p = s_p[e] / (float)TOKENS;
      lb += p * f;
      tail[e] = f;
    }
    lb *= (float)NE;
    tail[8] = z;
    tail[9] = z * 0.001f;
    tail[10] = lb;
    tail[11] = lb * 0.1f;
  }
}

// ---------------- GEMM1: H = silu(A@W1) * (A@W3);  A gathered rows of xb ----------------
// 1D swizzled grid; 2-phase dbuf global_load_lds prefetch; T2 XOR bank-swizzle:
// f(row)=(row>>1)&3 XOR'd into 16B-seg index on BOTH global source and LDS read.
__launch_bounds__(256, 2)
__global__ void gemm1_k(const u16* __restrict__ A, const u16* __restrict__ B1g,
                        const u16* __restrict__ B3g, u16* __restrict__ Hout,
                        const int* __restrict__ tok_list, const int* __restrict__ counts,
                        int Mfix, int MBg, int NBg) {
  constexpr int K = DM;
  constexpr int N = DFF;
  constexpr int NT = K / 32;
  // --- bijective XCD swizzle (nwg % 8 == 0), m varies fastest within chunk ---
  const int nwg = gridDim.x;
  const int cpx = nwg >> 3;
  const int wg = (blockIdx.x & 7) * cpx + (blockIdx.x >> 3);
  const int per = MBg * NBg;
  const int e = wg / per;
  const int rem = wg - e * per;
  const int m_blk = rem % MBg;
  const int n_blk = rem / MBg;
  int n_e = counts ? counts[e] : Mfix;
  if (counts && n_e > CAP) n_e = CAP;  // capacity clamp ONLY for routed experts
  const int m_base = m_blk * 128;
  if (m_base >= n_e) return;
  const int n_base = n_blk * 128;
  const size_t bstride = counts ? (size_t)N * K : 0;
  const u16* B1 = B1g + (size_t)e * bstride;
  const u16* B3 = B3g + (size_t)e * bstride;

  __shared__ __align__(16) u16 Als[2][128 * 32];
  __shared__ __align__(16) u16 B1ls[2][128 * 32];
  __shared__ __align__(16) u16 B3ls[2][128 * 32];

  const int tid = threadIdx.x;
  const int lane = tid & 63;
  const int w = tid >> 6;
  const int wm = w >> 1, wn = w & 1;
  const int lo = lane & 15, hi = lane >> 4;

  // ---- staging geometry: tile [128][32]u16 = 8 chunks of 1024B; wave w -> chunks {2w,2w+1}
  const int c0 = 2 * w;
  const int r0 = c0 * 16 + (lane >> 2);
  const int r1 = r0 + 16;
  const int sg = lane & 3;
  const int ssg = sg ^ ((lane >> 3) & 3);  // pre-swizzled global seg (f(row)=(row>>1)&3)

  size_t ar0, ar1;
  if (tok_list) {
    int g0i = m_base + r0; if (g0i >= n_e) g0i = n_e - 1;
    int g1i = m_base + r1; if (g1i >= n_e) g1i = n_e - 1;
    ar0 = (size_t)tok_list[e * CAP + g0i];
    ar1 = (size_t)tok_list[e * CAP + g1i];
  } else {
    ar0 = (size_t)(m_base + r0);
    ar1 = (size_t)(m_base + r1);
  }
  const u16* pA0 = A + ar0 * (size_t)K + ssg * 8;
  const u16* pA1 = A + ar1 * (size_t)K + ssg * 8;
  const u16* pB1a = B1 + (size_t)(n_base + r0) * K + ssg * 8;
  const u16* pB1b = B1 + (size_t)(n_base + r1) * K + ssg * 8;
  const u16* pB3a = B3 + (size_t)(n_base + r0) * K + ssg * 8;
  const u16* pB3b = B3 + (size_t)(n_base + r1) * K + ssg * 8;

  const int hsw = (hi ^ ((lo >> 1) & 3)) * 8;  // swizzled read seg (same involution)

  f32x4 acc1[4][4], acc3[4][4];
#pragma unroll
  for (int i = 0; i < 4; ++i)
#pragma unroll
    for (int j = 0; j < 4; ++j) { acc1[i][j] = (f32x4)0.f; acc3[i][j] = (f32x4)0.f; }

  auto compute = [&](const u16* rA, const u16* rB1, const u16* rB3) {
    bf16x8 af[4], b1f[4], b3f[4];
#pragma unroll
    for (int i = 0; i < 4; ++i) {
      af[i] = *(const bf16x8*)&rA[(wm * 64 + i * 16 + lo) * 32 + hsw];
      b1f[i] = *(const bf16x8*)&rB1[(wn * 64 + i * 16 + lo) * 32 + hsw];
      b3f[i] = *(const bf16x8*)&rB3[(wn * 64 + i * 16 + lo) * 32 + hsw];
    }
#pragma unroll
    for (int i = 0; i < 4; ++i)
#pragma unroll
      for (int j = 0; j < 4; ++j) {
        acc1[i][j] = __builtin_amdgcn_mfma_f32_16x16x32_bf16(af[i], b1f[j], acc1[i][j], 0, 0, 0);
        acc3[i][j] = __builtin_amdgcn_mfma_f32_16x16x32_bf16(af[i], b3f[j], acc3[i][j], 0, 0, 0);
      }
  };

  // prologue: stage tile 0 into buf 0
  GL16(pA0, &Als[0][c0 * 512]);  GL16(pA1, &Als[0][c0 * 512 + 512]);
  GL16(pB1a, &B1ls[0][c0 * 512]); GL16(pB1b, &B1ls[0][c0 * 512 + 512]);
  GL16(pB3a, &B3ls[0][c0 * 512]); GL16(pB3b, &B3ls[0][c0 * 512 + 512]);
  __syncthreads();
  int cur = 0;
  for (int kt = 0; kt < NT - 1; ++kt) {
    const int ko = (kt + 1) * 32;
    u16* sA = cur ? &Als[0][c0 * 512] : &Als[1][c0 * 512];
    u16* sB1 = cur ? &B1ls[0][c0 * 512] : &B1ls[1][c0 * 512];
    u16* sB3 = cur ? &B3ls[0][c0 * 512] : &B3ls[1][c0 * 512];
    GL16(pA0 + ko, sA);  GL16(pA1 + ko, sA + 512);
    GL16(pB1a + ko, sB1); GL16(pB1b + ko, sB1 + 512);
    GL16(pB3a + ko, sB3); GL16(pB3b + ko, sB3 + 512);
    compute(cur ? &Als[1][0] : &Als[0][0],
            cur ? &B1ls[1][0] : &B1ls[0][0],
            cur ? &B3ls[1][0] : &B3ls[0][0]);
    __syncthreads();  // drains vmcnt (stage done) after compute -> latency hidden
    cur ^= 1;
  }
  compute(cur ? &Als[1][0] : &Als[0][0],
          cur ? &B1ls[1][0] : &B1ls[0][0],
          cur ? &B3ls[1][0] : &B3ls[0][0]);

  const size_t orow0 = (counts ? (size_t)e * CAP : 0) + m_base;
#pragma unroll
  for (int i = 0; i < 4; ++i) {
#pragma unroll
    for (int r = 0; r < 4; ++r) {
      int rl = wm * 64 + i * 16 + hi * 4 + r;
      if (m_base + rl < n_e) {
        u16* orow = Hout + (orow0 + rl) * (size_t)N + n_base;
#pragma unroll
        for (int j = 0; j < 4; ++j) {
          float s1 = acc1[i][j][r], s3 = acc3[i][j][r];
          float hv = s1 / (1.f + __expf(-s1)) * s3;
          orow[wn * 64 + j * 16 + lo] = f2bf(hv);
        }
      }
    }
  }
}

// ---------------- GEMM2: Out = A@W2 ; A rows direct ----------------
__launch_bounds__(256, 2)
__global__ void gemm2_k(const u16* __restrict__ Ag, const u16* __restrict__ Bg,
                        void* __restrict__ Outv, const int* __restrict__ counts, int Mfix,
                        int outFloat, int MBg, int NBg) {
  constexpr int K = DFF;
  constexpr int N = DM;
  constexpr int NT = K / 32;
  const int nwg = gridDim.x;
  const int cpx = nwg >> 3;
  const int wg = (blockIdx.x & 7) * cpx + (blockIdx.x >> 3);
  const int per = MBg * NBg;
  const int e = wg / per;
  const int rem = wg - e * per;
  const int m_blk = rem % MBg;
  const int n_blk = rem / MBg;
  int n_e = counts ? counts[e] : Mfix;
  if (counts && n_e > CAP) n_e = CAP;  // capacity clamp ONLY for routed experts
  const int m_base = m_blk * 128;
  if (m_base >= n_e) return;
  const int n_base = n_blk * 128;
  const u16* A = Ag + (counts ? (size_t)e * CAP * K : 0);
  const u16* B = Bg + (counts ? (size_t)e * N * K : 0);

  __shared__ __align__(16) u16 Als[2][128 * 32];
  __shared__ __align__(16) u16 Bls[2][128 * 32];

  const int tid = threadIdx.x;
  const int lane = tid & 63;
  const int w = tid >> 6;
  const int wm = w >> 1, wn = w & 1;
  const int lo = lane & 15, hi = lane >> 4;

  const int c0 = 2 * w;
  const int r0 = c0 * 16 + (lane >> 2);
  const int r1 = r0 + 16;
  const int sg = lane & 3;
  const int ssg = sg ^ ((lane >> 3) & 3);

  const u16* pA0 = A + (size_t)(m_base + r0) * K + ssg * 8;
  const u16* pA1 = A + (size_t)(m_base + r1) * K + ssg * 8;
  const u16* pB0 = B + (size_t)(n_base + r0) * K + ssg * 8;
  const u16* pB1 = B + (size_t)(n_base + r1) * K + ssg * 8;

  const int hsw = (hi ^ ((lo >> 1) & 3)) * 8;

  f32x4 acc[4][4];
#pragma unroll
  for (int i = 0; i < 4; ++i)
#pragma unroll
    for (int j = 0; j < 4; ++j) acc[i][j] = (f32x4)0.f;

  auto compute = [&](const u16* rA, const u16* rB) {
    bf16x8 af[4], bfg[4];
#pragma unroll
    for (int i = 0; i < 4; ++i) {
      af[i] = *(const bf16x8*)&rA[(wm * 64 + i * 16 + lo) * 32 + hsw];
      bfg[i] = *(const bf16x8*)&rB[(wn * 64 + i * 16 + lo) * 32 + hsw];
    }
#pragma unroll
    for (int i = 0; i < 4; ++i)
#pragma unroll
      for (int j = 0; j < 4; ++j)
        acc[i][j] = __builtin_amdgcn_mfma_f32_16x16x32_bf16(af[i], bfg[j], acc[i][j], 0, 0, 0);
  };

  GL16(pA0, &Als[0][c0 * 512]); GL16(pA1, &Als[0][c0 * 512 + 512]);
  GL16(pB0, &Bls[0][c0 * 512]); GL16(pB1, &Bls[0][c0 * 512 + 512]);
  __syncthreads();
  int cur = 0;
  for (int kt = 0; kt < NT - 1; ++kt) {
    const int ko = (kt + 1) * 32;
    u16* sA = cur ? &Als[0][c0 * 512] : &Als[1][c0 * 512];
    u16* sB = cur ? &Bls[0][c0 * 512] : &Bls[1][c0 * 512];
    GL16(pA0 + ko, sA); GL16(pA1 + ko, sA + 512);
    GL16(pB0 + ko, sB); GL16(pB1 + ko, sB + 512);
    compute(cur ? &Als[1][0] : &Als[0][0], cur ? &Bls[1][0] : &Bls[0][0]);
    __syncthreads();
    cur ^= 1;
  }
  compute(cur ? &Als[1][0] : &Als[0][0], cur ? &Bls[1][0] : &Bls[0][0]);

#pragma unroll
  for (int i = 0; i < 4; ++i) {
#pragma unroll
    for (int r = 0; r < 4; ++r) {
      int rl = wm * 64 + i * 16 + hi * 4 + r;
      if (m_base + rl < n_e) {
        if (outFloat) {
          float* orow = (float*)Outv + (size_t)(m_base + rl) * N + n_base;
#pragma unroll
          for (int j = 0; j < 4; ++j) orow[wn * 64 + j * 16 + lo] = acc[i][j][r];
        } else {
          u16* orow = (u16*)Outv + ((size_t)e * CAP + m_base + rl) * N + n_base;
#pragma unroll
          for (int j = 0; j < 4; ++j) orow[wn * 64 + j * 16 + lo] = f2bf(acc[i][j][r]);
        }
      }
    }
  }
}

// ---------------- combine: xs[t] = g0*Y[e0][s0] + g1*Y[e1][s1] (bf16) ----------------
__global__ void combine_k(const u16* __restrict__ Y, const int* __restrict__ tok_e,
                          const int* __restrict__ tok_slot, const float* __restrict__ tok_gate,
                          u16* __restrict__ xs) {
  int u = blockIdx.x * 256 + threadIdx.x;
  int t = u >> 7;
  int seg = (u & 127) * 8;
  int e0 = tok_e[t * 2 + 0], e1 = tok_e[t * 2 + 1];
  int s0 = tok_slot[t * 2 + 0], s1 = tok_slot[t * 2 + 1];
  float g0 = tok_gate[t * 2 + 0], g1 = tok_gate[t * 2 + 1];
  u16x8 y0 = *(const u16x8*)(Y + ((size_t)e0 * CAP + s0) * DM + seg);
  u16x8 y1 = *(const u16x8*)(Y + ((size_t)e1 * CAP + s1) * DM + seg);
  u16x8 o;
#pragma unroll
  for (int j = 0; j < 8; ++j) o[j] = f2bf(g0 * bf2f(y0[j]) + g1 * bf2f(y1[j]));
  *(u16x8*)(xs + (size_t)t * DM + seg) = o;
}

// ---------------- host ----------------
extern "C" void kernel_launch(void* const* d_in, const int* in_sizes, int n_in, void* d_out,
                              int out_size, void* d_ws, size_t ws_size, hipStream_t stream) {
  const float* x = (const float*)d_in[0];
  const float* Wr = (const float*)d_in[1];
  const float* W1 = (const float*)d_in[2];
  const float* W2 = (const float*)d_in[3];
  const float* W3 = (const float*)d_in[4];
  const float* Ws1 = (const float*)d_in[5];
  const float* Ws2 = (const float*)d_in[6];
  const float* Ws3 = (const float*)d_in[7];
  float* out = (float*)d_out;
  (void)in_sizes; (void)n_in; (void)out_size; (void)ws_size;

  char* ws = (char*)d_ws;
  size_t o = 0;
  auto alloc = [&](size_t b) {
    void* p = ws + o;
    o = (o + b + 255) & ~(size_t)255;
    return p;
  };
  int* counters = (int*)alloc(NE * 4);
  int* tok_e = (int*)alloc(TOKENS * 2 * 4);
  int* tok_slot = (int*)alloc(TOKENS * 2 * 4);
  float* tok_gate = (float*)alloc(TOKENS * 2 * 4);
  float* tok_probs = (float*)alloc(TOKENS * NE * 4);
  float* tok_lse = (float*)alloc(TOKENS * 4);
  int* tok_list = (int*)alloc(NE * CAP * 4);
  u16* xb = (u16*)alloc((size_t)TOKENS * DM * 2);
  u16* W1t = (u16*)alloc((size_t)NE * DFF * DM * 2);
  u16* W3t = (u16*)alloc((size_t)NE * DFF * DM * 2);
  u16* W2t = (u16*)alloc((size_t)NE * DM * DFF * 2);
  u16* Ws1t = (u16*)alloc((size_t)DFF * DM * 2);
  u16* Ws3t = (u16*)alloc((size_t)DFF * DM * 2);
  u16* Ws2t = (u16*)alloc((size_t)DM * DFF * 2);
  u16* H = (u16*)alloc((size_t)NE * CAP * DFF * 2);
  u16* Y = (u16*)alloc((size_t)NE * CAP * DM * 2);
  u16* xs = (u16*)alloc((size_t)TOKENS * DM * 2);
  u16* Hs = (u16*)alloc((size_t)TOKENS * DFF * 2);

  zero_k<<<1, 64, 0, stream>>>(counters);
  conv_k<<<TOKENS * DM / 4 / 256, 256, 0, stream>>>(x, xb, TOKENS * DM / 4);
  tconv_k<<<dim3(DM / 64, DFF / 64, NE), 256, 0, stream>>>(W1, W1t, DM, DFF);
  tconv_k<<<dim3(DM / 64, DFF / 64, NE), 256, 0, stream>>>(W3, W3t, DM, DFF);
  tconv_k<<<dim3(DFF / 64, DM / 64, NE), 256, 0, stream>>>(W2, W2t, DFF, DM);
  tconv_k<<<dim3(DM / 64, DFF / 64, 1), 256, 0, stream>>>(Ws1, Ws1t, DM, DFF);
  tconv_k<<<dim3(DM / 64, DFF / 64, 1), 256, 0, stream>>>(Ws3, Ws3t, DM, DFF);
  tconv_k<<<dim3(DFF / 64, DM / 64, 1), 256, 0, stream>>>(Ws2, Ws2t, DFF, DM);
  router_k<<<TOKENS, 64, 0, stream>>>(x, Wr, counters, tok_list, tok_e, tok_slot, tok_gate,
                                      tok_probs, tok_lse);
  finalize_k<<<1, 256, 0, stream>>>(tok_probs, tok_lse, counters, out + (size_t)TOKENS * DM);
  // expert GEMM1: 16 m-blk x 16 n-blk x 8 experts = 2048 blocks (1D, XCD-swizzled)
  gemm1_k<<<16 * 16 * NE, 256, 0, stream>>>(xb, W1t, W3t, H, tok_list, counters, 0, 16, 16);
  // expert GEMM2: 16 x 8 x 8 = 1024 blocks
  gemm2_k<<<16 * 8 * NE, 256, 0, stream>>>(H, W2t, (void*)Y, counters, 0, 0, 16, 8);
  combine_k<<<TOKENS * DM / 8 / 256, 256, 0, stream>>>(Y, tok_e, tok_slot, tok_gate, xs);
  // shared GEMM1: 32 x 16 = 512 blocks
  gemm1_k<<<32 * 16, 256, 0, stream>>>(xs, Ws1t, Ws3t, Hs, nullptr, nullptr, TOKENS, 32, 16);
  // shared GEMM2: 32 x 8 = 256 blocks
  gemm2_k<<<32 * 8, 256, 0, stream>>>(Hs, Ws2t, (void*)out, nullptr, TOKENS, 1, 32, 8);
}